// Round 5
// baseline (474.168 us; speedup 1.0000x reference)
//
#include <hip/hip_runtime.h>
#include <hip/hip_bf16.h>

// (B,N,T,F) = (16,512,24,64). FP32 in/out.
#define BB 16
#define NN 512
#define TT 24
#define FF 64
#define OUT_OFF ((size_t)BB*NN*TT*FF)   // 12582912 floats (of | uf concatenated)

#define AIS 136      // Aj row stride, shorts (272B = 17*16B, odd 16B units)
#define XTS 72       // Xt/Ut/O/W row stride (144B = 9*16B, odd)
#define XTSZ 4672    // per-matrix region (64*72 + swizzle slack)

typedef __attribute__((ext_vector_type(8))) short v8s;
typedef __attribute__((ext_vector_type(16))) float v16f;

union U16x8 { uint4 v; unsigned short s[8]; };

__device__ inline v16f mfma32(v8s a, v8s b, v16f c) {
    return __builtin_amdgcn_mfma_f32_32x32x16_bf16(a, b, c, 0, 0, 0);
}

// ---- cheap bf16 conversion machinery (no NaN path; inputs are finite) ----
__device__ inline unsigned int fbits(float x) {
    union { float f; unsigned int u; } c; c.f = x; return c.u;
}
__device__ inline float ibits(unsigned int u) {
    union { float f; unsigned int u; } c; c.u = u; return c.f;
}
__device__ inline unsigned short f2bf_r(float x) {
    return (unsigned short)((fbits(x) + 0x8000u) >> 16);
}
__device__ inline void split8(const float* f, U16x8& H, U16x8& L) {
    #pragma unroll
    for (int k = 0; k < 8; ++k) {
        unsigned int u  = fbits(f[k]);
        unsigned int hr = (u + 0x8000u) & 0xffff0000u;
        H.s[k] = (unsigned short)(hr >> 16);
        float lo = f[k] - ibits(hr);
        L.s[k] = (unsigned short)((fbits(lo) + 0x8000u) >> 16);
    }
}
__device__ inline void cvt8h(const float* f, U16x8& H) {
    #pragma unroll
    for (int k = 0; k < 8; ++k) H.s[k] = f2bf_r(f[k]);
}

// pack two f32 (already bf16-representable) into one dword of 2 bf16 (exact)
__device__ inline unsigned int pkbf(float a, float b) {
    unsigned int r;
    asm("v_cvt_pk_bf16_f32 %0, %1, %2" : "=v"(r) : "v"(a), "v"(b));
    return r;
}

// C-layout (32x32) -> A-fragment repack, one K=16 chunk (c=0: j' 0..15, c=1: 16..31).
__device__ inline v8s pfrag(const float* cr, int c) {
    unsigned int a0 = pkbf(cr[8*c+0], cr[8*c+1]);
    unsigned int a1 = pkbf(cr[8*c+2], cr[8*c+3]);
    unsigned int b0 = pkbf(cr[8*c+4], cr[8*c+5]);
    unsigned int b1 = pkbf(cr[8*c+6], cr[8*c+7]);
    asm("v_permlane32_swap_b32 %0, %1" : "+v"(a0), "+v"(b0));
    asm("v_permlane32_swap_b32 %0, %1" : "+v"(a1), "+v"(b1));
    union { v8s v; unsigned int u[4]; } P;
    P.u[0] = a0; P.u[1] = a1; P.u[2] = b0; P.u[3] = b1;
    return P.v;
}

__global__ __launch_bounds__(256, 3)
void spag_kernel(const float* __restrict__ ori, const float* __restrict__ unc,
                 const float* __restrict__ emb, const float* __restrict__ W1,
                 float* __restrict__ out)
{
    // One 53504B arena; 3 blocks/CU fit LDS (3*53760 = 161280 <= 163840).
    // Regions (main loop): AjH[64*AIS] | AjL[64*AIS] | XT[XTSZ] | UT[XTSZ]
    // Prologue aliases AjH/AjL as Ai hi/lo staging (2 passes of 64 rows).
    // Epilogue re-carves the arena as Ox[128*XTS] | Ou[128*XTS] | Wt[64*XTS].
    __shared__ __align__(16) unsigned short SH[2*64*AIS + 2*XTSZ];
    unsigned short* AjH = SH;
    unsigned short* AjL = SH + 64*AIS;
    unsigned short* XT  = SH + 2*64*AIS;
    unsigned short* UT  = XT + XTSZ;

    const int tid  = threadIdx.x;
    // XCD-aware swizzle (bijective on [0,1536)): all 4 i-blocks of one (b,t)
    // land on the SAME XCD, adjacent in dispatch -> shared j-stream = L2 hits.
    const int xcd  = blockIdx.x & 7;
    const int slot = blockIdx.x >> 3;      // 0..191
    const int bt   = xcd * 48 + (slot >> 2);   // 0..383
    const int it   = slot & 3;
    const int b    = bt / TT, t = bt % TT;
    const int i0   = it * 128;

    const int lane = tid & 63;
    const int w    = tid >> 6;             // wave -> i rows w*32..w*32+31
    const int m    = lane & 31;
    const int hi   = lane >> 5;

    // staging thread mapping for j-tiles (64 rows x 64 f per tile)
    const int pj  = tid >> 3;              // j pair (2pj, 2pj+1)
    const int f0  = (tid & 7) * 8;         // f chunk
    const int jme = 2 * pj;

    // ---- prefetch j-tile 0 (ori, unc) into registers (T14 issue-early) ----
    float pa0[8], pa1[8], pu0[8], pu1[8];
    {
        const size_t r0 = ((size_t)((b*NN + jme)*TT + t))*FF + f0;
        const size_t r1 = r0 + (size_t)TT*FF;
        *(float4*)&pa0[0] = *(const float4*)(ori + r0);
        *(float4*)&pa0[4] = *(const float4*)(ori + r0 + 4);
        *(float4*)&pa1[0] = *(const float4*)(ori + r1);
        *(float4*)&pa1[4] = *(const float4*)(ori + r1 + 4);
        *(float4*)&pu0[0] = *(const float4*)(unc + r0);
        *(float4*)&pu0[4] = *(const float4*)(unc + r0 + 4);
        *(float4*)&pu1[0] = *(const float4*)(unc + r1);
        *(float4*)&pu1[4] = *(const float4*)(unc + r1 + 4);
    }

    // ---- prologue: stage Ai hi/lo in 2 passes of 64 rows, grab B-frags ----
    v8s bH[8], bL[8];   // i-side fragments, register-resident all kernel
    #pragma unroll
    for (int p = 0; p < 2; ++p) {
        {
            const int sr = tid >> 2, fc = (tid & 3) * 16;
            const float* xb = ori + ((size_t)((b*NN + i0 + p*64 + sr)*TT + t))*FF + fc;
            const float* eb = emb + (size_t)(i0 + p*64 + sr)*FF + fc;
            float tf[8]; U16x8 H, L;
            #pragma unroll
            for (int h = 0; h < 2; ++h) {
                *(float4*)&tf[0] = ((const float4*)xb)[2*h];
                *(float4*)&tf[4] = ((const float4*)xb)[2*h+1];
                split8(tf, H, L);
                *(uint4*)&AjH[sr*AIS + fc + h*8] = H.v;
                *(uint4*)&AjL[sr*AIS + fc + h*8] = L.v;
                *(float4*)&tf[0] = ((const float4*)eb)[2*h];
                *(float4*)&tf[4] = ((const float4*)eb)[2*h+1];
                split8(tf, H, L);
                *(uint4*)&AjH[sr*AIS + 64 + fc + h*8] = H.v;
                *(uint4*)&AjL[sr*AIS + 64 + fc + h*8] = L.v;
            }
        }
        __syncthreads();
        if ((w >> 1) == p) {
            const int lr = (w & 1)*32 + m;
            #pragma unroll
            for (int kk = 0; kk < 8; ++kk) {
                bH[kk] = *(const v8s*)&AjH[lr*AIS + kk*16 + hi*8];
                bL[kk] = *(const v8s*)&AjL[lr*AIS + kk*16 + hi*8];
            }
        }
        __syncthreads();
    }

    v16f accX0 = (v16f)(0.0f), accX1 = (v16f)(0.0f);
    v16f accU0 = (v16f)(0.0f), accU1 = (v16f)(0.0f);
    float rs    = 0.0f;   // softmax denom partial for row i = lane&31 (at m_run)
    float m_run = 0.0f;   // running row max of relu'd scores (>= 0)

    for (int jt = 0; jt < 8; ++jt) {
        const int j0 = jt * 64;
        __syncthreads();   // prev iter's LDS readers done (drains prefetch vmcnt)

        // ---- convert+write from prefetched regs; emb loaded here (L2-hot) ----
        {
            const int j = jme;
            U16x8 H0, L0, H1, L1;
            // ori: hi->AjH, lo->AjL, hi also transposed -> XT
            split8(pa0, H0, L0); split8(pa1, H1, L1);
            *(uint4*)&AjH[ j   *AIS + f0] = H0.v;
            *(uint4*)&AjH[(j+1)*AIS + f0] = H1.v;
            *(uint4*)&AjL[ j   *AIS + f0] = L0.v;
            *(uint4*)&AjL[(j+1)*AIS + f0] = L1.v;
            #pragma unroll
            for (int k = 0; k < 8; ++k) {
                int f = f0 + k;
                int off = f*XTS + (f>>4)*16 + j;
                *(unsigned int*)&XT[off] =
                    (unsigned int)H0.s[k] | ((unsigned int)H1.s[k] << 16);
            }
            // unc: hi only, transposed -> UT
            #pragma unroll
            for (int k = 0; k < 8; ++k) {
                int f = f0 + k;
                int off = f*XTS + (f>>4)*16 + j;
                *(unsigned int*)&UT[off] =
                    (unsigned int)f2bf_r(pu0[k]) | ((unsigned int)f2bf_r(pu1[k]) << 16);
            }
            // emb: hi->AjH(+64), lo->AjL(+64)
            const float* e0 = emb + (size_t)(j0 + j)*FF + f0;
            float t0[8], t1[8];
            *(float4*)&t0[0] = *(const float4*)(e0);
            *(float4*)&t0[4] = *(const float4*)(e0 + 4);
            *(float4*)&t1[0] = *(const float4*)(e0 + FF);
            *(float4*)&t1[4] = *(const float4*)(e0 + FF + 4);
            split8(t0, H0, L0); split8(t1, H1, L1);
            *(uint4*)&AjH[ j   *AIS + 64 + f0] = H0.v;
            *(uint4*)&AjH[(j+1)*AIS + 64 + f0] = H1.v;
            *(uint4*)&AjL[ j   *AIS + 64 + f0] = L0.v;
            *(uint4*)&AjL[(j+1)*AIS + 64 + f0] = L1.v;
        }
        __syncthreads();

        // ---- T14: issue next tile's global loads; latency hides under compute.
        // (Must be AFTER the barrier above: __syncthreads drains vmcnt(0).)
        if (jt < 7) {
            const size_t r0 = ((size_t)((b*NN + j0 + 64 + jme)*TT + t))*FF + f0;
            const size_t r1 = r0 + (size_t)TT*FF;
            *(float4*)&pa0[0] = *(const float4*)(ori + r0);
            *(float4*)&pa0[4] = *(const float4*)(ori + r0 + 4);
            *(float4*)&pa1[0] = *(const float4*)(ori + r1);
            *(float4*)&pa1[4] = *(const float4*)(ori + r1 + 4);
            *(float4*)&pu0[0] = *(const float4*)(unc + r0);
            *(float4*)&pu0[4] = *(const float4*)(unc + r0 + 4);
            *(float4*)&pu1[0] = *(const float4*)(unc + r1);
            *(float4*)&pu1[4] = *(const float4*)(unc + r1 + 4);
        }

        // ---- scores: C(S^T)[j][i], 32x32 tiles, hi/lo split (48 MFMA).
        // 4 independent accumulator chains (kk parity) -> latency-hiding;
        // merged with fp32 adds below.
        v16f C0a = (v16f)(0.0f), C0b = (v16f)(0.0f);
        v16f C1a = (v16f)(0.0f), C1b = (v16f)(0.0f);
        #pragma unroll
        for (int kk = 0; kk < 8; kk += 2) {
            const int fo0 = kk*16 + hi*8;
            const int fo1 = (kk+1)*16 + hi*8;
            v8s aH0a = *(const v8s*)&AjH[ m     *AIS + fo0];
            v8s aL0a = *(const v8s*)&AjL[ m     *AIS + fo0];
            v8s aH1a = *(const v8s*)&AjH[(32+m)*AIS + fo0];
            v8s aL1a = *(const v8s*)&AjL[(32+m)*AIS + fo0];
            v8s aH0b = *(const v8s*)&AjH[ m     *AIS + fo1];
            v8s aL0b = *(const v8s*)&AjL[ m     *AIS + fo1];
            v8s aH1b = *(const v8s*)&AjH[(32+m)*AIS + fo1];
            v8s aL1b = *(const v8s*)&AjL[(32+m)*AIS + fo1];
            C0a = mfma32(aH0a, bH[kk],   C0a);
            C1a = mfma32(aH1a, bH[kk],   C1a);
            C0b = mfma32(aH0b, bH[kk+1], C0b);
            C1b = mfma32(aH1b, bH[kk+1], C1b);
            C0a = mfma32(aH0a, bL[kk],   C0a);
            C1a = mfma32(aH1a, bL[kk],   C1a);
            C0b = mfma32(aH0b, bL[kk+1], C0b);
            C1b = mfma32(aH1b, bL[kk+1], C1b);
            C0a = mfma32(aL0a, bH[kk],   C0a);
            C1a = mfma32(aL1a, bH[kk],   C1a);
            C0b = mfma32(aL0b, bH[kk+1], C0b);
            C1b = mfma32(aL1b, bH[kk+1], C1b);
        }
        v16f C0, C1;
        #pragma unroll
        for (int r = 0; r < 16; ++r) { C0[r] = C0a[r] + C0b[r]; C1[r] = C1a[r] + C1b[r]; }

        // ---- online softmax with defer-max (T13, THR=8) ----
        float mt = 0.0f;
        #pragma unroll
        for (int r = 0; r < 16; ++r) {
            float s0 = fmaxf(C0[r], 0.0f); C0[r] = s0;
            float s1 = fmaxf(C1[r], 0.0f); C1[r] = s1;
            mt = fmaxf(mt, fmaxf(s0, s1));
        }
        mt = fmaxf(mt, __shfl_xor(mt, 32));
        if (!__all(mt <= m_run + 8.0f)) {
            float m_new = fmaxf(m_run, mt);
            float al = __expf(m_run - m_new);
            rs *= al; m_run = m_new;
            #pragma unroll
            for (int r = 0; r < 16; ++r) {
                float a = __shfl(al, (r & 3) + 8*(r >> 2) + 4*hi);
                accX0[r] *= a; accX1[r] *= a;
                accU0[r] *= a; accU1[r] *= a;
            }
        }

        // ---- p = exp(s - m_run), round to bf16, rowsum, repack to A-frags ----
        v8s P[4];
        {
            float cr[16];
            #pragma unroll
            for (int r = 0; r < 16; ++r) {
                float e = __expf(C0[r] - m_run);
                cr[r] = ibits((fbits(e) + 0x8000u) & 0xffff0000u);
                rs += cr[r];
            }
            P[0] = pfrag(cr, 0);
            P[1] = pfrag(cr, 1);
            #pragma unroll
            for (int r = 0; r < 16; ++r) {
                float e = __expf(C1[r] - m_run);
                cr[r] = ibits((fbits(e) + 0x8000u) & 0xffff0000u);
                rs += cr[r];
            }
            P[2] = pfrag(cr, 0);
            P[3] = pfrag(cr, 1);
        }

        // ---- PV: accX += P . x^T, accU += P . u^T (16 MFMA, 4 chains) ----
        #pragma unroll
        for (int kk = 0; kk < 4; ++kk) {
            const int fo = kk*16 + hi*8;
            v8s bx0 = *(const v8s*)&XT[ m     *XTS + (( m    )>>4)*16 + fo];
            v8s bu0 = *(const v8s*)&UT[ m     *XTS + (( m    )>>4)*16 + fo];
            v8s bx1 = *(const v8s*)&XT[(32+m)*XTS + (((32+m))>>4)*16 + fo];
            v8s bu1 = *(const v8s*)&UT[(32+m)*XTS + (((32+m))>>4)*16 + fo];
            accX0 = mfma32(P[kk], bx0, accX0);
            accX1 = mfma32(P[kk], bx1, accX1);
            accU0 = mfma32(P[kk], bu0, accU0);
            accU1 = mfma32(P[kk], bu1, accU1);
        }
    }

    // ---- epilogue: normalize, O.W1^T, relu, fp32 stores ----
    __syncthreads();                           // all PV reads done
    rs += __shfl_xor(rs, 32);                  // full row sum (>= 1)
    float inv = 1.0f / rs;

    unsigned short* Ox = SH;                   // [128][XTS]
    unsigned short* Ou = SH + 128*XTS;         // [128][XTS]
    unsigned short* Wt = SH + 256*XTS;         // [64][XTS]

    #pragma unroll
    for (int r = 0; r < 16; ++r) {
        int il = (r & 3) + 8*(r >> 2) + 4*hi;
        float iv = __shfl(inv, il);
        int row = w*32 + il;
        Ox[row*XTS + m]      = f2bf_r(accX0[r] * iv);
        Ox[row*XTS + 32 + m] = f2bf_r(accX1[r] * iv);
        Ou[row*XTS + m]      = f2bf_r(accU0[r] * iv);
        Ou[row*XTS + 32 + m] = f2bf_r(accU1[r] * iv);
    }
    // W1 tile (hi only) -> Wt
    {
        const int sr = tid >> 2, fc = (tid & 3) * 16;
        const float* wb = W1 + sr*FF + fc;
        float tf[8]; U16x8 H;
        #pragma unroll
        for (int h = 0; h < 2; ++h) {
            *(float4*)&tf[0] = ((const float4*)wb)[2*h];
            *(float4*)&tf[4] = ((const float4*)wb)[2*h+1];
            cvt8h(tf, H);
            *(uint4*)&Wt[sr*XTS + fc + h*8] = H.v;
        }
    }
    __syncthreads();

    v8s ao[4], aq[4];
    #pragma unroll
    for (int kk = 0; kk < 4; ++kk) {
        const int fo = kk*16 + hi*8;
        ao[kk] = *(const v8s*)&Ox[(w*32 + m)*XTS + fo];
        aq[kk] = *(const v8s*)&Ou[(w*32 + m)*XTS + fo];
    }
    #pragma unroll
    for (int ot = 0; ot < 2; ++ot) {
        v16f ax = (v16f)(0.0f), au = (v16f)(0.0f);
        #pragma unroll
        for (int kk = 0; kk < 4; ++kk) {
            const int fo = kk*16 + hi*8;
            v8s bw = *(const v8s*)&Wt[(ot*32 + m)*XTS + fo];
            ax = mfma32(ao[kk], bw, ax);
            au = mfma32(aq[kk], bw, au);
        }
        #pragma unroll
        for (int r = 0; r < 16; ++r) {
            int il = (r & 3) + 8*(r >> 2) + 4*hi;
            int i = i0 + w*32 + il;
            int o = ot*32 + m;
            size_t idx = ((size_t)((b*NN + i)*TT + t))*FF + o;
            out[idx]           = fmaxf(ax[r], 0.0f);
            out[OUT_OFF + idx] = fmaxf(au[r], 0.0f);
        }
    }
}

extern "C" void kernel_launch(void* const* d_in, const int* in_sizes, int n_in,
                              void* d_out, int out_size, void* d_ws, size_t ws_size,
                              hipStream_t stream) {
    const float* ori = (const float*)d_in[0];
    const float* unc = (const float*)d_in[1];
    const float* emb = (const float*)d_in[2];
    const float* W1  = (const float*)d_in[3];
    float* out = (float*)d_out;

    spag_kernel<<<dim3(BB*TT*4), dim3(256), 0, stream>>>(ori, unc, emb, W1, out);
}

// Round 6
// 254.844 us; speedup vs baseline: 1.8606x; 1.8606x over previous
//
#include <hip/hip_runtime.h>
#include <hip/hip_bf16.h>

// (B,N,T,F) = (16,512,24,64). FP32 in/out.
#define BB 16
#define NN 512
#define TT 24
#define FF 64
#define OUT_OFF ((size_t)BB*NN*TT*FF)   // 12582912 floats (of | uf concatenated)

#define AIS 136      // Aj row stride, shorts (272B = 17*16B, odd 16B units)
#define XTS 72       // Xt/Ut/O/W row stride (144B = 9*16B, odd)
#define XTSZ 4672    // per-matrix region (64*72 + swizzle slack)

typedef __attribute__((ext_vector_type(8))) short v8s;
typedef __attribute__((ext_vector_type(16))) float v16f;

union U16x8 { uint4 v; unsigned int u[4]; unsigned short s[8]; };

__device__ inline v16f mfma32(v8s a, v8s b, v16f c) {
    return __builtin_amdgcn_mfma_f32_32x32x16_bf16(a, b, c, 0, 0, 0);
}

// ---- bf16 conversion machinery (no NaN path; inputs are finite) ----
__device__ inline unsigned int fbits(float x) {
    union { float f; unsigned int u; } c; c.f = x; return c.u;
}
__device__ inline float ibits(unsigned int u) {
    union { float f; unsigned int u; } c; c.u = u; return c.f;
}
__device__ inline unsigned short f2bf_r(float x) {
    return (unsigned short)((fbits(x) + 0x8000u) >> 16);
}
// pack two f32 into one dword of 2 bf16 (RNE), 1 VALU op
__device__ inline unsigned int pkbf(float a, float b) {
    unsigned int r;
    asm("v_cvt_pk_bf16_f32 %0, %1, %2" : "=v"(r) : "v"(a), "v"(b));
    return r;
}
// hi/lo split via cvt_pk: hi = RNE bf16 (packed pair), lo = bf16(f - hi) exact residual.
// ~3 VALU ops/element (was 6).
__device__ inline void split8(const float* f, U16x8& H, U16x8& L) {
    #pragma unroll
    for (int k = 0; k < 4; ++k) {
        unsigned int hp = pkbf(f[2*k], f[2*k+1]);
        float h0 = ibits(hp << 16);
        float h1 = ibits(hp & 0xffff0000u);
        L.u[k] = pkbf(f[2*k] - h0, f[2*k+1] - h1);
        H.u[k] = hp;
    }
}
__device__ inline void cvt8h(const float* f, U16x8& H) {
    #pragma unroll
    for (int k = 0; k < 8; ++k) H.s[k] = f2bf_r(f[k]);
}

// C-layout (32x32) -> A-fragment repack, one K=16 chunk (c=0: j' 0..15, c=1: 16..31).
__device__ inline v8s pfrag(const float* cr, int c) {
    unsigned int a0 = pkbf(cr[8*c+0], cr[8*c+1]);
    unsigned int a1 = pkbf(cr[8*c+2], cr[8*c+3]);
    unsigned int b0 = pkbf(cr[8*c+4], cr[8*c+5]);
    unsigned int b1 = pkbf(cr[8*c+6], cr[8*c+7]);
    asm("v_permlane32_swap_b32 %0, %1" : "+v"(a0), "+v"(b0));
    asm("v_permlane32_swap_b32 %0, %1" : "+v"(a1), "+v"(b1));
    union { v8s v; unsigned int u[4]; } P;
    P.u[0] = a0; P.u[1] = a1; P.u[2] = b0; P.u[3] = b1;
    return P.v;
}

__global__ __launch_bounds__(256, 2)
void spag_kernel(const float* __restrict__ ori, const float* __restrict__ unc,
                 const float* __restrict__ emb, const float* __restrict__ W1,
                 float* __restrict__ out)
{
    // 72192B arena, 2 blocks/CU (144.4KB <= 160KB LDS). Regions (main loop):
    //   AjH[64*AIS] | AjL[64*AIS] | XT0|UT0 | XT1|UT1   (XT/UT double-buffered
    // for deferred PV). Prologue aliases AjH/AjL as Ai staging. Epilogue
    // re-carves SH[0..23040] as Ox[128*XTS] | Ou[128*XTS] | Wt[64*XTS]
    // (does not touch XT1/UT1, which PV(7) reads just before).
    __shared__ __align__(16) unsigned short SH[2*64*AIS + 4*XTSZ];
    unsigned short* AjH = SH;
    unsigned short* AjL = SH + 64*AIS;
    unsigned short* XTb = SH + 2*64*AIS;   // + buf*2*XTSZ ; UT = XT + XTSZ

    const int tid  = threadIdx.x;
    // XCD-aware swizzle (bijective on [0,1536)): all 4 i-blocks of one (b,t)
    // land on the SAME XCD, adjacent in dispatch -> shared j-stream = L2 hits.
    const int xcd  = blockIdx.x & 7;
    const int slot = blockIdx.x >> 3;      // 0..191
    const int bt   = xcd * 48 + (slot >> 2);   // 0..383
    const int it   = slot & 3;
    const int b    = bt / TT, t = bt % TT;
    const int i0   = it * 128;

    const int lane = tid & 63;
    const int w    = tid >> 6;             // wave -> i rows w*32..w*32+31
    const int m    = lane & 31;
    const int hi   = lane >> 5;

    // staging thread mapping for j-tiles (64 rows x 64 f per tile)
    const int pj  = tid >> 3;              // j pair (2pj, 2pj+1)
    const int f0  = (tid & 7) * 8;         // f chunk
    const int jme = 2 * pj;

    // ---- prefetch j-tile 0 (ori, unc) into registers (T14 issue-early) ----
    float pa0[8], pa1[8], pu0[8], pu1[8];
    {
        const size_t r0 = ((size_t)((b*NN + jme)*TT + t))*FF + f0;
        const size_t r1 = r0 + (size_t)TT*FF;
        *(float4*)&pa0[0] = *(const float4*)(ori + r0);
        *(float4*)&pa0[4] = *(const float4*)(ori + r0 + 4);
        *(float4*)&pa1[0] = *(const float4*)(ori + r1);
        *(float4*)&pa1[4] = *(const float4*)(ori + r1 + 4);
        *(float4*)&pu0[0] = *(const float4*)(unc + r0);
        *(float4*)&pu0[4] = *(const float4*)(unc + r0 + 4);
        *(float4*)&pu1[0] = *(const float4*)(unc + r1);
        *(float4*)&pu1[4] = *(const float4*)(unc + r1 + 4);
    }

    // ---- prologue: stage Ai hi/lo in 2 passes of 64 rows, grab B-frags ----
    v8s bH[8], bL[8];   // i-side fragments, register-resident all kernel
    #pragma unroll
    for (int p = 0; p < 2; ++p) {
        {
            const int sr = tid >> 2, fc = (tid & 3) * 16;
            const float* xb = ori + ((size_t)((b*NN + i0 + p*64 + sr)*TT + t))*FF + fc;
            const float* eb = emb + (size_t)(i0 + p*64 + sr)*FF + fc;
            float tf[8]; U16x8 H, L;
            #pragma unroll
            for (int h = 0; h < 2; ++h) {
                *(float4*)&tf[0] = ((const float4*)xb)[2*h];
                *(float4*)&tf[4] = ((const float4*)xb)[2*h+1];
                split8(tf, H, L);
                *(uint4*)&AjH[sr*AIS + fc + h*8] = H.v;
                *(uint4*)&AjL[sr*AIS + fc + h*8] = L.v;
                *(float4*)&tf[0] = ((const float4*)eb)[2*h];
                *(float4*)&tf[4] = ((const float4*)eb)[2*h+1];
                split8(tf, H, L);
                *(uint4*)&AjH[sr*AIS + 64 + fc + h*8] = H.v;
                *(uint4*)&AjL[sr*AIS + 64 + fc + h*8] = L.v;
            }
        }
        __syncthreads();
        if ((w >> 1) == p) {
            const int lr = (w & 1)*32 + m;
            #pragma unroll
            for (int kk = 0; kk < 8; ++kk) {
                bH[kk] = *(const v8s*)&AjH[lr*AIS + kk*16 + hi*8];
                bL[kk] = *(const v8s*)&AjL[lr*AIS + kk*16 + hi*8];
            }
        }
        __syncthreads();
    }

    v16f accX0 = (v16f)(0.0f), accX1 = (v16f)(0.0f);
    v16f accU0 = (v16f)(0.0f), accU1 = (v16f)(0.0f);
    float rs    = 0.0f;   // softmax denom partial for row i = lane&31 (at m_run)
    float m_run = 0.0f;   // running row max of relu'd scores (>= 0)
    v8s Pv[4];            // deferred-PV fragments (tile jt-1), live across barrier

    for (int jt = 0; jt < 8; ++jt) {
        const int j0 = jt * 64;
        unsigned short* XT = XTb + (jt & 1)*2*XTSZ;
        unsigned short* UT = XT + XTSZ;
        __syncthreads();   // QK(jt-1) AjH reads + PV(jt-2) XT-buf reads done

        // ---- convert+write from prefetched regs; emb loaded here (L2-hot) ----
        {
            const int j = jme;
            U16x8 H0, L0, H1, L1;
            // ori: hi->AjH, lo->AjL; hi also transposed -> XT (direct pkbf)
            split8(pa0, H0, L0); split8(pa1, H1, L1);
            *(uint4*)&AjH[ j   *AIS + f0] = H0.v;
            *(uint4*)&AjH[(j+1)*AIS + f0] = H1.v;
            *(uint4*)&AjL[ j   *AIS + f0] = L0.v;
            *(uint4*)&AjL[(j+1)*AIS + f0] = L1.v;
            #pragma unroll
            for (int k = 0; k < 8; ++k) {
                int f = f0 + k;
                int off = f*XTS + (f>>4)*16 + j;
                *(unsigned int*)&XT[off] = pkbf(pa0[k], pa1[k]);
                *(unsigned int*)&UT[off] = pkbf(pu0[k], pu1[k]);
            }
            // emb: hi->AjH(+64), lo->AjL(+64)
            const float* e0 = emb + (size_t)(j0 + j)*FF + f0;
            float t0[8], t1[8];
            *(float4*)&t0[0] = *(const float4*)(e0);
            *(float4*)&t0[4] = *(const float4*)(e0 + 4);
            *(float4*)&t1[0] = *(const float4*)(e0 + FF);
            *(float4*)&t1[4] = *(const float4*)(e0 + FF + 4);
            split8(t0, H0, L0); split8(t1, H1, L1);
            *(uint4*)&AjH[ j   *AIS + 64 + f0] = H0.v;
            *(uint4*)&AjH[(j+1)*AIS + 64 + f0] = H1.v;
            *(uint4*)&AjL[ j   *AIS + 64 + f0] = L0.v;
            *(uint4*)&AjL[(j+1)*AIS + 64 + f0] = L1.v;
        }
        __syncthreads();

        // ---- T14: issue next tile's global loads; latency hides under compute.
        // (Must be AFTER the barrier above: __syncthreads drains vmcnt(0).)
        if (jt < 7) {
            const size_t r0 = ((size_t)((b*NN + j0 + 64 + jme)*TT + t))*FF + f0;
            const size_t r1 = r0 + (size_t)TT*FF;
            *(float4*)&pa0[0] = *(const float4*)(ori + r0);
            *(float4*)&pa0[4] = *(const float4*)(ori + r0 + 4);
            *(float4*)&pa1[0] = *(const float4*)(ori + r1);
            *(float4*)&pa1[4] = *(const float4*)(ori + r1 + 4);
            *(float4*)&pu0[0] = *(const float4*)(unc + r0);
            *(float4*)&pu0[4] = *(const float4*)(unc + r0 + 4);
            *(float4*)&pu1[0] = *(const float4*)(unc + r1);
            *(float4*)&pu1[4] = *(const float4*)(unc + r1 + 4);
        }

        // ---- deferred PV(jt-1): reads the OTHER XT/UT buffer; interleaves
        // with QK(jt) MFMAs below (independent chains, no barrier between) ----
        if (jt > 0) {
            unsigned short* XTp = XTb + ((jt & 1) ^ 1)*2*XTSZ;
            unsigned short* UTp = XTp + XTSZ;
            #pragma unroll
            for (int kk = 0; kk < 4; ++kk) {
                const int fo = kk*16 + hi*8;
                v8s bx0 = *(const v8s*)&XTp[ m     *XTS + (( m    )>>4)*16 + fo];
                v8s bu0 = *(const v8s*)&UTp[ m     *XTS + (( m    )>>4)*16 + fo];
                v8s bx1 = *(const v8s*)&XTp[(32+m)*XTS + (((32+m))>>4)*16 + fo];
                v8s bu1 = *(const v8s*)&UTp[(32+m)*XTS + (((32+m))>>4)*16 + fo];
                accX0 = mfma32(Pv[kk], bx0, accX0);
                accX1 = mfma32(Pv[kk], bx1, accX1);
                accU0 = mfma32(Pv[kk], bu0, accU0);
                accU1 = mfma32(Pv[kk], bu1, accU1);
            }
        }

        // ---- scores: C(S^T)[j][i], 32x32 tiles, hi/lo split (48 MFMA) ----
        v16f C0 = (v16f)(0.0f), C1 = (v16f)(0.0f);
        #pragma unroll
        for (int kk = 0; kk < 8; ++kk) {
            const int fo = kk*16 + hi*8;
            v8s aH0 = *(const v8s*)&AjH[ m     *AIS + fo];
            v8s aL0 = *(const v8s*)&AjL[ m     *AIS + fo];
            v8s aH1 = *(const v8s*)&AjH[(32+m)*AIS + fo];
            v8s aL1 = *(const v8s*)&AjL[(32+m)*AIS + fo];
            C0 = mfma32(aH0, bH[kk], C0);
            C1 = mfma32(aH1, bH[kk], C1);
            C0 = mfma32(aH0, bL[kk], C0);
            C1 = mfma32(aH1, bL[kk], C1);
            C0 = mfma32(aL0, bH[kk], C0);
            C1 = mfma32(aL1, bH[kk], C1);
        }

        // ---- online softmax with defer-max (T13, THR=8) ----
        // NOTE: rescale happens BEFORE this tile's PV is applied (next iter),
        // so acc is at scale m_run(jt) when P(jt) (computed at m_run(jt)) lands.
        float mt = 0.0f;
        #pragma unroll
        for (int r = 0; r < 16; ++r) {
            float s0 = fmaxf(C0[r], 0.0f); C0[r] = s0;
            float s1 = fmaxf(C1[r], 0.0f); C1[r] = s1;
            mt = fmaxf(mt, fmaxf(s0, s1));
        }
        mt = fmaxf(mt, __shfl_xor(mt, 32));
        if (!__all(mt <= m_run + 8.0f)) {
            float m_new = fmaxf(m_run, mt);
            float al = __expf(m_run - m_new);
            rs *= al; m_run = m_new;
            #pragma unroll
            for (int r = 0; r < 16; ++r) {
                float a = __shfl(al, (r & 3) + 8*(r >> 2) + 4*hi);
                accX0[r] *= a; accX1[r] *= a;
                accU0[r] *= a; accU1[r] *= a;
            }
        }

        // ---- p = exp(s - m_run); rs from unrounded e (pfrag's cvt_pk rounds;
        // mismatch ~2^-9 relative -> ~1e-3 output error, negligible) ----
        {
            float cr[16];
            #pragma unroll
            for (int r = 0; r < 16; ++r) {
                float e = __expf(C0[r] - m_run);
                cr[r] = e;
                rs += e;
            }
            Pv[0] = pfrag(cr, 0);
            Pv[1] = pfrag(cr, 1);
            #pragma unroll
            for (int r = 0; r < 16; ++r) {
                float e = __expf(C1[r] - m_run);
                cr[r] = e;
                rs += e;
            }
            Pv[2] = pfrag(cr, 0);
            Pv[3] = pfrag(cr, 1);
        }
    }

    // ---- final PV (tile 7, buffer 1) ----
    {
        unsigned short* XTp = XTb + 2*XTSZ;
        unsigned short* UTp = XTp + XTSZ;
        #pragma unroll
        for (int kk = 0; kk < 4; ++kk) {
            const int fo = kk*16 + hi*8;
            v8s bx0 = *(const v8s*)&XTp[ m     *XTS + (( m    )>>4)*16 + fo];
            v8s bu0 = *(const v8s*)&UTp[ m     *XTS + (( m    )>>4)*16 + fo];
            v8s bx1 = *(const v8s*)&XTp[(32+m)*XTS + (((32+m))>>4)*16 + fo];
            v8s bu1 = *(const v8s*)&UTp[(32+m)*XTS + (((32+m))>>4)*16 + fo];
            accX0 = mfma32(Pv[kk], bx0, accX0);
            accX1 = mfma32(Pv[kk], bx1, accX1);
            accU0 = mfma32(Pv[kk], bu0, accU0);
            accU1 = mfma32(Pv[kk], bu1, accU1);
        }
    }

    // ---- epilogue: normalize, O.W1^T, relu, fp32 stores ----
    __syncthreads();                           // all QK/PV LDS reads done
    rs += __shfl_xor(rs, 32);                  // full row sum (>= 1)
    float inv = 1.0f / rs;

    unsigned short* Ox = SH;                   // [128][XTS]
    unsigned short* Ou = SH + 128*XTS;         // [128][XTS]
    unsigned short* Wt = SH + 256*XTS;         // [64][XTS]  (ends at 23040 < XT1)

    #pragma unroll
    for (int r = 0; r < 16; ++r) {
        int il = (r & 3) + 8*(r >> 2) + 4*hi;
        float iv = __shfl(inv, il);
        int row = w*32 + il;
        Ox[row*XTS + m]      = f2bf_r(accX0[r] * iv);
        Ox[row*XTS + 32 + m] = f2bf_r(accX1[r] * iv);
        Ou[row*XTS + m]      = f2bf_r(accU0[r] * iv);
        Ou[row*XTS + 32 + m] = f2bf_r(accU1[r] * iv);
    }
    // W1 tile (hi only) -> Wt
    {
        const int sr = tid >> 2, fc = (tid & 3) * 16;
        const float* wb = W1 + sr*FF + fc;
        float tf[8]; U16x8 H;
        #pragma unroll
        for (int h = 0; h < 2; ++h) {
            *(float4*)&tf[0] = ((const float4*)wb)[2*h];
            *(float4*)&tf[4] = ((const float4*)wb)[2*h+1];
            cvt8h(tf, H);
            *(uint4*)&Wt[sr*XTS + fc + h*8] = H.v;
        }
    }
    __syncthreads();

    v8s ao[4], aq[4];
    #pragma unroll
    for (int kk = 0; kk < 4; ++kk) {
        const int fo = kk*16 + hi*8;
        ao[kk] = *(const v8s*)&Ox[(w*32 + m)*XTS + fo];
        aq[kk] = *(const v8s*)&Ou[(w*32 + m)*XTS + fo];
    }
    #pragma unroll
    for (int ot = 0; ot < 2; ++ot) {
        v16f ax = (v16f)(0.0f), au = (v16f)(0.0f);
        #pragma unroll
        for (int kk = 0; kk < 4; ++kk) {
            const int fo = kk*16 + hi*8;
            v8s bw = *(const v8s*)&Wt[(ot*32 + m)*XTS + fo];
            ax = mfma32(ao[kk], bw, ax);
            au = mfma32(aq[kk], bw, au);
        }
        #pragma unroll
        for (int r = 0; r < 16; ++r) {
            int il = (r & 3) + 8*(r >> 2) + 4*hi;
            int i = i0 + w*32 + il;
            int o = ot*32 + m;
            size_t idx = ((size_t)((b*NN + i)*TT + t))*FF + o;
            out[idx]           = fmaxf(ax[r], 0.0f);
            out[OUT_OFF + idx] = fmaxf(au[r], 0.0f);
        }
    }
}

extern "C" void kernel_launch(void* const* d_in, const int* in_sizes, int n_in,
                              void* d_out, int out_size, void* d_ws, size_t ws_size,
                              hipStream_t stream) {
    const float* ori = (const float*)d_in[0];
    const float* unc = (const float*)d_in[1];
    const float* emb = (const float*)d_in[2];
    const float* W1  = (const float*)d_in[3];
    float* out = (float*)d_out;

    spag_kernel<<<dim3(BB*TT*4), dim3(256), 0, stream>>>(ori, unc, emb, W1, out);
}